// Round 3
// baseline (201.109 us; speedup 1.0000x reference)
//
#include <hip/hip_runtime.h>
#include <math.h>

#define NFFT 1024
#define HOP 256
#define NFREQ 513
#define TFRAMES 1024
#define NT_TILE 16
#define LOUT  262400        /* (1024 + 256*1023) - 512 */
#define TILE_SAMPS 4864     /* 16*256 + 768 */

__device__ __forceinline__ float2 cadd(float2 a, float2 b){ return make_float2(a.x+b.x, a.y+b.y); }
__device__ __forceinline__ float2 csub(float2 a, float2 b){ return make_float2(a.x-b.x, a.y-b.y); }
__device__ __forceinline__ float2 muli(float2 a){ return make_float2(-a.y, a.x); }   // * i
__device__ __forceinline__ float2 cmul(float2 a, float2 b){
    return make_float2(a.x*b.x - a.y*b.y, a.x*b.y + a.y*b.x);
}

// inverse-sign (e^{+2pi i/8}) radix-8 DFT on 8 named registers — no arrays, no spill
__device__ __forceinline__ void radix8_inv(float2& v0, float2& v1, float2& v2, float2& v3,
                                           float2& v4, float2& v5, float2& v6, float2& v7) {
    const float C = 0.70710678118654752f;
    float2 a0 = cadd(v0, v4), a1 = csub(v0, v4);
    float2 a2 = cadd(v2, v6), a3 = csub(v2, v6);
    float2 b0 = cadd(v1, v5), b1 = csub(v1, v5);
    float2 b2 = cadd(v3, v7), b3 = csub(v3, v7);
    float2 E0 = cadd(a0, a2), E2 = csub(a0, a2);
    float2 E1 = cadd(a1, muli(a3)), E3 = csub(a1, muli(a3));
    float2 O0 = cadd(b0, b2), O2 = csub(b0, b2);
    float2 O1 = cadd(b1, muli(b3)), O3 = csub(b1, muli(b3));
    float2 T1 = make_float2(C*(O1.x - O1.y),  C*(O1.x + O1.y));   // O1 * w8
    float2 T2 = muli(O2);                                          // O2 * w8^2
    float2 T3 = make_float2(-C*(O3.x + O3.y), C*(O3.x - O3.y));    // O3 * w8^3
    v0 = cadd(E0, O0); v4 = csub(E0, O0);
    v1 = cadd(E1, T1); v5 = csub(E1, T1);
    v2 = cadd(E2, T2); v6 = csub(E2, T2);
    v3 = cadd(E3, T3); v7 = csub(E3, T3);
}

// Tw[m] = e^{+2pi i m/512}, m in [0,512) via 256-entry table + sign fold
__device__ __forceinline__ float2 twget(const float2* Tw, int m) {
    float2 t = Tw[m & 255];
    float s = (m & 256) ? -1.f : 1.f;
    return make_float2(s * t.x, s * t.y);
}

// phase-1 storage position of natural index n (0..511), XOR-swizzled within 64-blocks
__device__ __forceinline__ int zpos(int n) {
    int blk = n >> 6;
    return blk * 64 + ((n & 63) ^ ((9 * blk) & 63));
}
// storage position of natural FFT OUTPUT index m (octal-digit-reversed + swizzle)
__device__ __forceinline__ int opos(int m) {
    int k0 = m & 7, k1 = (m >> 3) & 7, k2 = m >> 6;
    return k0 * 64 + (((k1 << 3) | k2) ^ ((9 * k0) & 63));
}

// LDS: Zc 32768 + Carry 3072 + Tw 2048 = 37888 B -> 4 blocks/CU (151552 <= 163840),
// 32 waves/CU possible at VGPR<=64. No OA accumulator: samples sl<2048 finalize in
// half 0, sl>=2816 in half 1; only the 768-sample seam [2048,2816) is carried in LDS.
__global__ __launch_bounds__(512, 4) void istft_kernel(const float2* __restrict__ x,
                                                       float* __restrict__ out) {
    __shared__ float2 Zc[8 * 512];    // 32768 B
    __shared__ float2 Carry[384];     //  3072 B (seam samples [2048,2816), pair-packed)
    __shared__ float2 Tw[256];        //  2048 B

    const int tid  = threadIdx.x;
    const int bc   = blockIdx.y;
    const int tile = blockIdx.x;
    const int t0   = tile * NT_TILE;
    const int S0   = t0 * HOP;

    if (tid < 256) {
        float s, c;
        __sincosf((float)tid * (6.283185307179586f / 512.f), &s, &c);
        Tw[tid] = make_float2(c, s);
    }
    __syncthreads();   // Tw ready before phase 1 reads it

    const int f     = tid >> 6;      // wave-private frame (0..7)
    const int lane6 = tid & 63;
    const int fbase = f << 9;
    const int fx    = f << 1;        // per-frame bank swizzle (replaces FSTR pad)

    // half-step rotation e^{+i pi/512} for odd phase-1 bins (and the window)
    const float HR = 0.99998117528260111f, HI = 0.00613588464915448f;

    for (int half = 0; half < 2; ++half) {
        // ---------- phase 1: global load + pack half-size spectrum ----------
        {
            const int kg = tid >> 3, tt = tid & 7;
            const int tg = t0 + half * 8 + tt;
            const long baseIn = (long)bc * ((long)NFREQ * TFRAMES);
            const int wbase = tt << 9;
            const int fxw = tt << 1;
            #pragma unroll
            for (int i = 0; i < 5; ++i) {
                int kp = kg + 64 * i;
                if (kp <= 256) {
                    float2 A = x[baseIn + (long)kp * TFRAMES + tg];
                    float2 B = x[baseIn + (long)(512 - kp) * TFRAMES + tg];
                    if (kp == 0) { A.y = 0.f; B.y = 0.f; }  // c2r drops DC/Nyquist imag
                    // e^{+2pi i kp/1024} from table: Tw[kp>>1], odd kp rotated half-step
                    float2 tw = Tw[kp >> 1];
                    if (kp & 1) tw = make_float2(tw.x * HR - tw.y * HI, tw.x * HI + tw.y * HR);
                    float d2r = A.x - B.x, d2i = A.y + B.y;
                    float o2r = tw.x * d2r - tw.y * d2i, o2i = tw.x * d2i + tw.y * d2r;
                    float s2r = A.x + B.x, s2i = A.y - B.y;
                    Zc[wbase + (zpos(kp) ^ fxw)] = make_float2(0.5f * (s2r - o2i), 0.5f * (s2i + o2r));
                    if (kp >= 1 && kp <= 255)
                        Zc[wbase + (zpos(512 - kp) ^ fxw)] = make_float2(0.5f * (s2r + o2i), 0.5f * (o2r - s2i));
                }
            }
        }
        __syncthreads();

        // ---------- radix-8 DIF stage 1 (stride 64) — wave-private, no barriers ----------
        {
            const int j = lane6, jx = lane6 ^ fx, zb = fbase;
            float2 v0 = Zc[zb +       (jx ^  0)];
            float2 v1 = Zc[zb +  64 + (jx ^  9)];
            float2 v2 = Zc[zb + 128 + (jx ^ 18)];
            float2 v3 = Zc[zb + 192 + (jx ^ 27)];
            float2 v4 = Zc[zb + 256 + (jx ^ 36)];
            float2 v5 = Zc[zb + 320 + (jx ^ 45)];
            float2 v6 = Zc[zb + 384 + (jx ^ 54)];
            float2 v7 = Zc[zb + 448 + (jx ^ 63)];
            radix8_inv(v0, v1, v2, v3, v4, v5, v6, v7);
            Zc[zb +       (jx ^  0)] = v0;
            Zc[zb +  64 + (jx ^  9)] = cmul(v1, twget(Tw, j));
            Zc[zb + 128 + (jx ^ 18)] = cmul(v2, twget(Tw, 2 * j));
            Zc[zb + 192 + (jx ^ 27)] = cmul(v3, twget(Tw, 3 * j));
            Zc[zb + 256 + (jx ^ 36)] = cmul(v4, twget(Tw, 4 * j));
            Zc[zb + 320 + (jx ^ 45)] = cmul(v5, twget(Tw, 5 * j));
            Zc[zb + 384 + (jx ^ 54)] = cmul(v6, twget(Tw, 6 * j));
            Zc[zb + 448 + (jx ^ 63)] = cmul(v7, twget(Tw, 7 * j));
        }
        // ---------- stage 2 (stride 8 within 64-blocks) ----------
        {
            const int b = lane6 >> 3, jp = lane6 & 7;
            const int sw = ((9 * b) & 63) ^ fx, bb = fbase + 64 * b;
            float2 v0 = Zc[bb + ((jp     ) ^ sw)];
            float2 v1 = Zc[bb + ((jp +  8) ^ sw)];
            float2 v2 = Zc[bb + ((jp + 16) ^ sw)];
            float2 v3 = Zc[bb + ((jp + 24) ^ sw)];
            float2 v4 = Zc[bb + ((jp + 32) ^ sw)];
            float2 v5 = Zc[bb + ((jp + 40) ^ sw)];
            float2 v6 = Zc[bb + ((jp + 48) ^ sw)];
            float2 v7 = Zc[bb + ((jp + 56) ^ sw)];
            radix8_inv(v0, v1, v2, v3, v4, v5, v6, v7);
            const int m1 = 8 * jp;
            Zc[bb + ((jp     ) ^ sw)] = v0;
            Zc[bb + ((jp +  8) ^ sw)] = cmul(v1, twget(Tw, m1));
            Zc[bb + ((jp + 16) ^ sw)] = cmul(v2, twget(Tw, 2 * m1));
            Zc[bb + ((jp + 24) ^ sw)] = cmul(v3, twget(Tw, 3 * m1));
            Zc[bb + ((jp + 32) ^ sw)] = cmul(v4, twget(Tw, 4 * m1));
            Zc[bb + ((jp + 40) ^ sw)] = cmul(v5, twget(Tw, 5 * m1));
            Zc[bb + ((jp + 48) ^ sw)] = cmul(v6, twget(Tw, 6 * m1));
            Zc[bb + ((jp + 56) ^ sw)] = cmul(v7, twget(Tw, 7 * m1));
        }
        // ---------- stage 3 (contiguous groups of 8, no twiddle) ----------
        {
            const int b = lane6 >> 3, g = lane6 & 7;
            const int sw = ((9 * b) & 63) ^ fx, bb = fbase + 64 * b, g8 = 8 * g;
            float2 v0 = Zc[bb + ((g8    ) ^ sw)];
            float2 v1 = Zc[bb + ((g8 + 1) ^ sw)];
            float2 v2 = Zc[bb + ((g8 + 2) ^ sw)];
            float2 v3 = Zc[bb + ((g8 + 3) ^ sw)];
            float2 v4 = Zc[bb + ((g8 + 4) ^ sw)];
            float2 v5 = Zc[bb + ((g8 + 5) ^ sw)];
            float2 v6 = Zc[bb + ((g8 + 6) ^ sw)];
            float2 v7 = Zc[bb + ((g8 + 7) ^ sw)];
            radix8_inv(v0, v1, v2, v3, v4, v5, v6, v7);
            Zc[bb + ((g8    ) ^ sw)] = v0;
            Zc[bb + ((g8 + 1) ^ sw)] = v1;
            Zc[bb + ((g8 + 2) ^ sw)] = v2;
            Zc[bb + ((g8 + 3) ^ sw)] = v3;
            Zc[bb + ((g8 + 4) ^ sw)] = v4;
            Zc[bb + ((g8 + 5) ^ sw)] = v5;
            Zc[bb + ((g8 + 6) ^ sw)] = v6;
            Zc[bb + ((g8 + 7) ^ sw)] = v7;
        }
        __syncthreads();

        // ---------- window + overlap-add: register accumulate -> direct global store ----------
        if (half == 0) {
            // pairs pi in [0,1408): sl = 2*pi in [0,2816)
            #pragma unroll
            for (int r = 0; r < 3; ++r) {
                int pi = tid + 512 * r;
                if (pi < 1408) {
                    int sl  = pi << 1;
                    int slh = sl >> 8;
                    int tlo = max(slh - 3, 0), thi = min(slh, 7);
                    float ae = 0.f, ao = 0.f;
                    for (int tl = tlo; tl <= thi; ++tl) {
                        int n  = sl - (tl << 8);          // 0..1022, even
                        int m  = n >> 1;
                        float2 zz = Zc[(tl << 9) + (opos(m) ^ (tl << 1))];
                        float2 t  = Tw[m & 255];
                        float sg  = (m & 256) ? -1.f : 1.f;
                        float ce  = sg * t.x;                       // cos(2pi n/1024)
                        float co  = sg * (t.x * HR - t.y * HI);     // cos(2pi (n+1)/1024)
                        ae += zz.x * (1.f - ce);
                        ao += zz.y * (1.f - co);
                    }
                    ae *= 0.015625f; ao *= 0.015625f;     // sqrt(1024)*0.5/512/2 folded
                    if (pi < 1024) {                      // sl < 2048: final after half 0
                        int s = S0 + sl;
                        if (pi >= 384) {                  // sl >= 768: tile-interior
                            reinterpret_cast<float2*>(out)[(bc * LOUT + (s - 512)) >> 1] =
                                make_float2(ae, ao);
                        } else if (s >= 512) {            // head seam with previous tile
                            atomicAdd(&out[bc * LOUT + (s - 512)], ae);
                            atomicAdd(&out[bc * LOUT + (s - 511)], ao);
                        }
                    } else {                              // sl in [2048,2816): carry seam
                        Carry[pi - 1024] = make_float2(ae, ao);
                    }
                }
            }
        } else {
            // pairs q in [0,1408): sl = 2048 + 2*q in [2048,4864)
            #pragma unroll
            for (int r = 0; r < 3; ++r) {
                int q = tid + 512 * r;
                if (q < 1408) {
                    int sl  = 2048 + (q << 1);
                    int slh = sl >> 8;
                    int tlo = max(slh - 3, 8), thi = min(slh, 15);
                    float ae = 0.f, ao = 0.f;
                    for (int tl = tlo; tl <= thi; ++tl) {
                        int fr = tl - 8;
                        int n  = sl - (tl << 8);          // 0..1022, even
                        int m  = n >> 1;
                        float2 zz = Zc[(fr << 9) + (opos(m) ^ (fr << 1))];
                        float2 t  = Tw[m & 255];
                        float sg  = (m & 256) ? -1.f : 1.f;
                        float ce  = sg * t.x;
                        float co  = sg * (t.x * HR - t.y * HI);
                        ae += zz.x * (1.f - ce);
                        ao += zz.y * (1.f - co);
                    }
                    ae *= 0.015625f; ao *= 0.015625f;
                    if (q < 384) { float2 c = Carry[q]; ae += c.x; ao += c.y; }
                    int s = S0 + sl;
                    int o = bc * LOUT + (s - 512);
                    if (sl < 4096) {                      // tile-interior
                        reinterpret_cast<float2*>(out)[o >> 1] = make_float2(ae, ao);
                    } else {                              // tail seam with next tile
                        atomicAdd(&out[o],     ae);
                        atomicAdd(&out[o + 1], ao);
                    }
                }
            }
        }
        __syncthreads();   // protect Zc (and order Carry) before next half's phase 1
    }
}

extern "C" void kernel_launch(void* const* d_in, const int* in_sizes, int n_in,
                              void* d_out, int out_size, void* d_ws, size_t ws_size,
                              hipStream_t stream) {
    const float2* x = (const float2*)d_in[0];
    float* out = (float*)d_out;
    (void)in_sizes; (void)n_in; (void)d_ws; (void)ws_size;

    hipMemsetAsync(d_out, 0, (size_t)out_size * sizeof(float), stream);

    dim3 grid(TFRAMES / NT_TILE, 64);   // 64 tiles x 64 (B*C) rows
    dim3 block(512);
    istft_kernel<<<grid, block, 0, stream>>>(x, out);
}

// Round 4
// 148.875 us; speedup vs baseline: 1.3509x; 1.3509x over previous
//
#include <hip/hip_runtime.h>
#include <math.h>

#define NFFT 1024
#define HOP 256
#define NFREQ 513
#define TFRAMES 1024
#define NT_TILE 16
#define LOUT  262400        /* (1024 + 256*1023) - 512 */
#define TILE_SAMPS 4864     /* 16*256 + 768 */
#define NPAIR 2432          /* TILE_SAMPS/2 */

__device__ __forceinline__ float2 cadd(float2 a, float2 b){ return make_float2(a.x+b.x, a.y+b.y); }
__device__ __forceinline__ float2 csub(float2 a, float2 b){ return make_float2(a.x-b.x, a.y-b.y); }
__device__ __forceinline__ float2 muli(float2 a){ return make_float2(-a.y, a.x); }   // * i
__device__ __forceinline__ float2 cmul(float2 a, float2 b){
    return make_float2(a.x*b.x - a.y*b.y, a.x*b.y + a.y*b.x);
}

// inverse-sign (e^{+2pi i/8}) radix-8 DFT on 8 named registers — no arrays, no spill
__device__ __forceinline__ void radix8_inv(float2& v0, float2& v1, float2& v2, float2& v3,
                                           float2& v4, float2& v5, float2& v6, float2& v7) {
    const float C = 0.70710678118654752f;
    float2 a0 = cadd(v0, v4), a1 = csub(v0, v4);
    float2 a2 = cadd(v2, v6), a3 = csub(v2, v6);
    float2 b0 = cadd(v1, v5), b1 = csub(v1, v5);
    float2 b2 = cadd(v3, v7), b3 = csub(v3, v7);
    float2 E0 = cadd(a0, a2), E2 = csub(a0, a2);
    float2 E1 = cadd(a1, muli(a3)), E3 = csub(a1, muli(a3));
    float2 O0 = cadd(b0, b2), O2 = csub(b0, b2);
    float2 O1 = cadd(b1, muli(b3)), O3 = csub(b1, muli(b3));
    float2 T1 = make_float2(C*(O1.x - O1.y),  C*(O1.x + O1.y));   // O1 * w8
    float2 T2 = muli(O2);                                          // O2 * w8^2
    float2 T3 = make_float2(-C*(O3.x + O3.y), C*(O3.x - O3.y));    // O3 * w8^3
    v0 = cadd(E0, O0); v4 = csub(E0, O0);
    v1 = cadd(E1, T1); v5 = csub(E1, T1);
    v2 = cadd(E2, T2); v6 = csub(E2, T2);
    v3 = cadd(E3, T3); v7 = csub(E3, T3);
}

// Tw[m] = e^{+2pi i m/512}, m in [0,512) via 256-entry table + sign fold
__device__ __forceinline__ float2 twget(const float2* Tw, int m) {
    float2 t = Tw[m & 255];
    float s = (m & 256) ? -1.f : 1.f;
    return make_float2(s * t.x, s * t.y);
}

// phase-1 storage position of natural index n (0..511), XOR-swizzled within 64-blocks
__device__ __forceinline__ int zpos(int n) {
    int blk = n >> 6;
    return blk * 64 + ((n & 63) ^ ((9 * blk) & 63));
}

// LDS: Zc 32768 + OA 19456 + Tw 2048 = 54272 B (R2 layout, known-good codegen).
// launch_bounds stays (512,4): tighter bounds force spills (R1: +450 MB scratch).
__global__ __launch_bounds__(512, 4) void istft_kernel(const float2* __restrict__ x,
                                                       float* __restrict__ out) {
    __shared__ float2 Zc[8 * 512];    // 32768 B
    __shared__ float2 OA[NPAIR];      // 19456 B (even/odd sample pairs)
    __shared__ float2 Tw[256];        //  2048 B

    const int tid  = threadIdx.x;
    const int bc   = blockIdx.y;
    const int tile = blockIdx.x;
    const int t0   = tile * NT_TILE;
    const int S0   = t0 * HOP;

    if (tid < 256) {
        float s, c;
        __sincosf((float)tid * (6.283185307179586f / 512.f), &s, &c);
        Tw[tid] = make_float2(c, s);
    }
    #pragma unroll
    for (int r = 0; r < 5; ++r) { int p = tid + 512 * r; if (p < NPAIR) OA[p] = make_float2(0.f, 0.f); }
    __syncthreads();   // Tw ready before phase 1 reads it

    const int f     = tid >> 6;      // wave-private frame (0..7)
    const int lane6 = tid & 63;
    const int fbase = f << 9;
    const int fx    = f << 1;        // per-frame bank swizzle (replaces FSTR pad)

    // half-step rotation e^{+i pi/512} for odd phase-1 bins (and the window)
    const float HR = 0.99998117528260111f, HI = 0.00613588464915448f;

    for (int half = 0; half < 2; ++half) {
        // ---------- phase 1: global load + pack half-size spectrum ----------
        {
            const int kg = tid >> 3, tt = tid & 7;
            const int tg = t0 + half * 8 + tt;
            const long baseIn = (long)bc * ((long)NFREQ * TFRAMES);
            const int wbase = tt << 9;
            const int fxw = tt << 1;
            #pragma unroll
            for (int i = 0; i < 5; ++i) {
                int kp = kg + 64 * i;
                if (kp <= 256) {
                    float2 A = x[baseIn + (long)kp * TFRAMES + tg];
                    float2 B = x[baseIn + (long)(512 - kp) * TFRAMES + tg];
                    if (kp == 0) { A.y = 0.f; B.y = 0.f; }  // c2r drops DC/Nyquist imag
                    // e^{+2pi i kp/1024} from table: Tw[kp>>1], odd kp rotated half-step
                    float2 tw = Tw[kp >> 1];
                    if (kp & 1) tw = make_float2(tw.x * HR - tw.y * HI, tw.x * HI + tw.y * HR);
                    float d2r = A.x - B.x, d2i = A.y + B.y;
                    float o2r = tw.x * d2r - tw.y * d2i, o2i = tw.x * d2i + tw.y * d2r;
                    float s2r = A.x + B.x, s2i = A.y - B.y;
                    Zc[wbase + (zpos(kp) ^ fxw)] = make_float2(0.5f * (s2r - o2i), 0.5f * (s2i + o2r));
                    if (kp >= 1 && kp <= 255)
                        Zc[wbase + (zpos(512 - kp) ^ fxw)] = make_float2(0.5f * (s2r + o2i), 0.5f * (o2r - s2i));
                }
            }
        }
        __syncthreads();

        // ---------- radix-8 DIF stage 1 (stride 64) — wave-private, no barriers ----------
        {
            const int j = lane6, jx = lane6 ^ fx, zb = fbase;
            float2 v0 = Zc[zb +       (jx ^  0)];
            float2 v1 = Zc[zb +  64 + (jx ^  9)];
            float2 v2 = Zc[zb + 128 + (jx ^ 18)];
            float2 v3 = Zc[zb + 192 + (jx ^ 27)];
            float2 v4 = Zc[zb + 256 + (jx ^ 36)];
            float2 v5 = Zc[zb + 320 + (jx ^ 45)];
            float2 v6 = Zc[zb + 384 + (jx ^ 54)];
            float2 v7 = Zc[zb + 448 + (jx ^ 63)];
            radix8_inv(v0, v1, v2, v3, v4, v5, v6, v7);
            Zc[zb +       (jx ^  0)] = v0;
            Zc[zb +  64 + (jx ^  9)] = cmul(v1, twget(Tw, j));
            Zc[zb + 128 + (jx ^ 18)] = cmul(v2, twget(Tw, 2 * j));
            Zc[zb + 192 + (jx ^ 27)] = cmul(v3, twget(Tw, 3 * j));
            Zc[zb + 256 + (jx ^ 36)] = cmul(v4, twget(Tw, 4 * j));
            Zc[zb + 320 + (jx ^ 45)] = cmul(v5, twget(Tw, 5 * j));
            Zc[zb + 384 + (jx ^ 54)] = cmul(v6, twget(Tw, 6 * j));
            Zc[zb + 448 + (jx ^ 63)] = cmul(v7, twget(Tw, 7 * j));
        }
        // ---------- stage 2 (stride 8 within 64-blocks) ----------
        {
            const int b = lane6 >> 3, jp = lane6 & 7;
            const int sw = ((9 * b) & 63) ^ fx, bb = fbase + 64 * b;
            float2 v0 = Zc[bb + ((jp     ) ^ sw)];
            float2 v1 = Zc[bb + ((jp +  8) ^ sw)];
            float2 v2 = Zc[bb + ((jp + 16) ^ sw)];
            float2 v3 = Zc[bb + ((jp + 24) ^ sw)];
            float2 v4 = Zc[bb + ((jp + 32) ^ sw)];
            float2 v5 = Zc[bb + ((jp + 40) ^ sw)];
            float2 v6 = Zc[bb + ((jp + 48) ^ sw)];
            float2 v7 = Zc[bb + ((jp + 56) ^ sw)];
            radix8_inv(v0, v1, v2, v3, v4, v5, v6, v7);
            const int m1 = 8 * jp;
            Zc[bb + ((jp     ) ^ sw)] = v0;
            Zc[bb + ((jp +  8) ^ sw)] = cmul(v1, twget(Tw, m1));
            Zc[bb + ((jp + 16) ^ sw)] = cmul(v2, twget(Tw, 2 * m1));
            Zc[bb + ((jp + 24) ^ sw)] = cmul(v3, twget(Tw, 3 * m1));
            Zc[bb + ((jp + 32) ^ sw)] = cmul(v4, twget(Tw, 4 * m1));
            Zc[bb + ((jp + 40) ^ sw)] = cmul(v5, twget(Tw, 5 * m1));
            Zc[bb + ((jp + 48) ^ sw)] = cmul(v6, twget(Tw, 6 * m1));
            Zc[bb + ((jp + 56) ^ sw)] = cmul(v7, twget(Tw, 7 * m1));
        }
        // ---------- stage 3 (contiguous groups of 8, no twiddle) ----------
        {
            const int b = lane6 >> 3, g = lane6 & 7;
            const int sw = ((9 * b) & 63) ^ fx, bb = fbase + 64 * b, g8 = 8 * g;
            float2 v0 = Zc[bb + ((g8    ) ^ sw)];
            float2 v1 = Zc[bb + ((g8 + 1) ^ sw)];
            float2 v2 = Zc[bb + ((g8 + 2) ^ sw)];
            float2 v3 = Zc[bb + ((g8 + 3) ^ sw)];
            float2 v4 = Zc[bb + ((g8 + 4) ^ sw)];
            float2 v5 = Zc[bb + ((g8 + 5) ^ sw)];
            float2 v6 = Zc[bb + ((g8 + 6) ^ sw)];
            float2 v7 = Zc[bb + ((g8 + 7) ^ sw)];
            radix8_inv(v0, v1, v2, v3, v4, v5, v6, v7);
            Zc[bb + ((g8    ) ^ sw)] = v0;
            Zc[bb + ((g8 + 1) ^ sw)] = v1;
            Zc[bb + ((g8 + 2) ^ sw)] = v2;
            Zc[bb + ((g8 + 3) ^ sw)] = v3;
            Zc[bb + ((g8 + 4) ^ sw)] = v4;
            Zc[bb + ((g8 + 5) ^ sw)] = v5;
            Zc[bb + ((g8 + 6) ^ sw)] = v6;
            Zc[bb + ((g8 + 7) ^ sw)] = v7;
        }
        __syncthreads();

        // ---------- window + overlap-add into LDS accumulator ----------
        // Lean tap loop: one Tw read per thread; (ce,se) rotated by exact quarter
        // turns (m steps by -128 = pi/2); opos(m) updated incrementally (k0,k1
        // invariant across taps, only k2 -= 2; no borrow since m mod 64 const).
        {
            const int h8 = half * 8;
            #pragma unroll
            for (int r = 0; r < 3; ++r) {
                int pi = (half ? 1024 : 0) + tid + 512 * r;
                if (pi < (half ? NPAIR : 1408)) {
                    int slh = pi >> 7;                       // sl>>8 with sl=2*pi
                    int tlo = max(slh - 3, h8), thi = min(slh, h8 + 7);
                    int m0  = pi - (tlo << 7);               // in [0,512)
                    int k0  = m0 & 7;
                    int hi  = ((m0 >> 3) & 7) << 3;
                    int k2v = m0 >> 6;
                    int sw9 = (9 * k0) & 63;
                    float2 t0c = Tw[m0 & 255];
                    float sg = (m0 & 256) ? -1.f : 1.f;
                    float ce = sg * t0c.x, se = sg * t0c.y;
                    float ae = 0.f, ao = 0.f;
                    int cb = ((tlo - h8) << 9) + (k0 << 6);
                    for (int fr = tlo - h8; fr <= thi - h8; ++fr) {
                        int low = ((hi | k2v) ^ sw9) ^ (fr << 1);
                        float2 zz = Zc[cb + low];
                        float co = ce * HR - se * HI;        // odd-sample window angle
                        ae += zz.x * (1.f - ce);
                        ao += zz.y * (1.f - co);
                        float nc = se; se = -ce; ce = nc;    // rotate -pi/2 (exact)
                        k2v -= 2; cb += 512;
                    }
                    float2 o = OA[pi];
                    o.x += ae * 0.015625f;   // sqrt(1024)*0.5/512/2 folded
                    o.y += ao * 0.015625f;
                    OA[pi] = o;
                }
            }
        }
        __syncthreads();   // protect Zc before next half's phase 1
    }

    // ---------- writeout: interior float2 store, boundaries atomic ----------
    #pragma unroll
    for (int r = 0; r < 5; ++r) {
        int pi = tid + 512 * r;
        if (pi < NPAIR) {
            int sl = pi << 1;
            int s  = S0 + sl;
            float2 v = OA[pi];
            if (pi >= 384 && pi < 2048) {        // sl in [768, 4096): tile-interior
                reinterpret_cast<float2*>(out)[(bc * LOUT + (s - 512)) >> 1] = v;
            } else if (s >= 512) {               // head-trim: s even, so s>=512 covers s+1 too
                atomicAdd(&out[bc * LOUT + (s - 512)], v.x);
                atomicAdd(&out[bc * LOUT + (s - 511)], v.y);
            }
        }
    }
}

extern "C" void kernel_launch(void* const* d_in, const int* in_sizes, int n_in,
                              void* d_out, int out_size, void* d_ws, size_t ws_size,
                              hipStream_t stream) {
    const float2* x = (const float2*)d_in[0];
    float* out = (float*)d_out;
    (void)in_sizes; (void)n_in; (void)d_ws; (void)ws_size;

    hipMemsetAsync(d_out, 0, (size_t)out_size * sizeof(float), stream);

    dim3 grid(TFRAMES / NT_TILE, 64);   // 64 tiles x 64 (B*C) rows
    dim3 block(512);
    istft_kernel<<<grid, block, 0, stream>>>(x, out);
}

// Round 5
// 129.545 us; speedup vs baseline: 1.5524x; 1.1492x over previous
//
#include <hip/hip_runtime.h>
#include <math.h>

#define NFFT 1024
#define HOP 256
#define NFREQ 513
#define TFRAMES 1024
#define NT_TILE 8           /* 8 frames per block: one former "half" */
#define LOUT  262400        /* (1024 + 256*1023) - 512 */
#define NPAIR 1408          /* pairs per block: samples [0, 2816) */

__device__ __forceinline__ float2 cadd(float2 a, float2 b){ return make_float2(a.x+b.x, a.y+b.y); }
__device__ __forceinline__ float2 csub(float2 a, float2 b){ return make_float2(a.x-b.x, a.y-b.y); }
__device__ __forceinline__ float2 muli(float2 a){ return make_float2(-a.y, a.x); }   // * i
__device__ __forceinline__ float2 cmul(float2 a, float2 b){
    return make_float2(a.x*b.x - a.y*b.y, a.x*b.y + a.y*b.x);
}

// inverse-sign (e^{+2pi i/8}) radix-8 DFT on 8 named registers — no arrays, no spill
__device__ __forceinline__ void radix8_inv(float2& v0, float2& v1, float2& v2, float2& v3,
                                           float2& v4, float2& v5, float2& v6, float2& v7) {
    const float C = 0.70710678118654752f;
    float2 a0 = cadd(v0, v4), a1 = csub(v0, v4);
    float2 a2 = cadd(v2, v6), a3 = csub(v2, v6);
    float2 b0 = cadd(v1, v5), b1 = csub(v1, v5);
    float2 b2 = cadd(v3, v7), b3 = csub(v3, v7);
    float2 E0 = cadd(a0, a2), E2 = csub(a0, a2);
    float2 E1 = cadd(a1, muli(a3)), E3 = csub(a1, muli(a3));
    float2 O0 = cadd(b0, b2), O2 = csub(b0, b2);
    float2 O1 = cadd(b1, muli(b3)), O3 = csub(b1, muli(b3));
    float2 T1 = make_float2(C*(O1.x - O1.y),  C*(O1.x + O1.y));   // O1 * w8
    float2 T2 = muli(O2);                                          // O2 * w8^2
    float2 T3 = make_float2(-C*(O3.x + O3.y), C*(O3.x - O3.y));    // O3 * w8^3
    v0 = cadd(E0, O0); v4 = csub(E0, O0);
    v1 = cadd(E1, T1); v5 = csub(E1, T1);
    v2 = cadd(E2, T2); v6 = csub(E2, T2);
    v3 = cadd(E3, T3); v7 = csub(E3, T3);
}

// Tw[m] = e^{+2pi i m/512}, m in [0,512) via 256-entry table + sign fold
__device__ __forceinline__ float2 twget(const float2* Tw, int m) {
    float2 t = Tw[m & 255];
    float s = (m & 256) ? -1.f : 1.f;
    return make_float2(s * t.x, s * t.y);
}

// phase-1 storage position of natural index n (0..511), XOR-swizzled within 64-blocks
__device__ __forceinline__ int zpos(int n) {
    int blk = n >> 6;
    return blk * 64 + ((n & 63) ^ ((9 * blk) & 63));
}

// LDS: Zc 32768 + Tw 2048 = 34816 B -> 4 blocks/CU (139264 <= 163840, 24K headroom).
// No OA accumulator: OLA accumulates in registers and stores directly; 8-frame-group
// seams all go through atomics onto the memset-zeroed output.
// launch_bounds stays (512,4): tighter bounds force spills (R1: +450 MB scratch).
__global__ __launch_bounds__(512, 4) void istft_kernel(const float2* __restrict__ x,
                                                       float* __restrict__ out) {
    __shared__ float2 Zc[8 * 512];    // 32768 B
    __shared__ float2 Tw[256];        //  2048 B

    const int tid  = threadIdx.x;
    const int bc   = blockIdx.y;
    const int tile = blockIdx.x;
    const int t0   = tile * NT_TILE;
    const int S0   = t0 * HOP;

    if (tid < 256) {
        float s, c;
        __sincosf((float)tid * (6.283185307179586f / 512.f), &s, &c);
        Tw[tid] = make_float2(c, s);
    }
    __syncthreads();   // Tw ready before phase 1 reads it

    const int f     = tid >> 6;      // wave-private frame (0..7)
    const int lane6 = tid & 63;
    const int fbase = f << 9;
    const int fx    = f << 1;        // per-frame bank swizzle (replaces stride pad)

    // half-step rotation e^{+i pi/512} for odd phase-1 bins (and the window)
    const float HR = 0.99998117528260111f, HI = 0.00613588464915448f;

    // ---------- phase 1: global load + pack half-size spectrum ----------
    {
        const int kg = tid >> 3, tt = tid & 7;
        const int tg = t0 + tt;
        const long baseIn = (long)bc * ((long)NFREQ * TFRAMES);
        const int wbase = tt << 9;
        const int fxw = tt << 1;
        #pragma unroll
        for (int i = 0; i < 5; ++i) {
            int kp = kg + 64 * i;
            if (kp <= 256) {
                float2 A = x[baseIn + (long)kp * TFRAMES + tg];
                float2 B = x[baseIn + (long)(512 - kp) * TFRAMES + tg];
                if (kp == 0) { A.y = 0.f; B.y = 0.f; }  // c2r drops DC/Nyquist imag
                // e^{+2pi i kp/1024} from table: Tw[kp>>1], odd kp rotated half-step
                float2 tw = Tw[kp >> 1];
                if (kp & 1) tw = make_float2(tw.x * HR - tw.y * HI, tw.x * HI + tw.y * HR);
                float d2r = A.x - B.x, d2i = A.y + B.y;
                float o2r = tw.x * d2r - tw.y * d2i, o2i = tw.x * d2i + tw.y * d2r;
                float s2r = A.x + B.x, s2i = A.y - B.y;
                Zc[wbase + (zpos(kp) ^ fxw)] = make_float2(0.5f * (s2r - o2i), 0.5f * (s2i + o2r));
                if (kp >= 1 && kp <= 255)
                    Zc[wbase + (zpos(512 - kp) ^ fxw)] = make_float2(0.5f * (s2r + o2i), 0.5f * (o2r - s2i));
            }
        }
    }
    __syncthreads();

    // ---------- radix-8 DIF stage 1 (stride 64) — wave-private, no barriers ----------
    {
        const int j = lane6, jx = lane6 ^ fx, zb = fbase;
        float2 v0 = Zc[zb +       (jx ^  0)];
        float2 v1 = Zc[zb +  64 + (jx ^  9)];
        float2 v2 = Zc[zb + 128 + (jx ^ 18)];
        float2 v3 = Zc[zb + 192 + (jx ^ 27)];
        float2 v4 = Zc[zb + 256 + (jx ^ 36)];
        float2 v5 = Zc[zb + 320 + (jx ^ 45)];
        float2 v6 = Zc[zb + 384 + (jx ^ 54)];
        float2 v7 = Zc[zb + 448 + (jx ^ 63)];
        radix8_inv(v0, v1, v2, v3, v4, v5, v6, v7);
        Zc[zb +       (jx ^  0)] = v0;
        Zc[zb +  64 + (jx ^  9)] = cmul(v1, twget(Tw, j));
        Zc[zb + 128 + (jx ^ 18)] = cmul(v2, twget(Tw, 2 * j));
        Zc[zb + 192 + (jx ^ 27)] = cmul(v3, twget(Tw, 3 * j));
        Zc[zb + 256 + (jx ^ 36)] = cmul(v4, twget(Tw, 4 * j));
        Zc[zb + 320 + (jx ^ 45)] = cmul(v5, twget(Tw, 5 * j));
        Zc[zb + 384 + (jx ^ 54)] = cmul(v6, twget(Tw, 6 * j));
        Zc[zb + 448 + (jx ^ 63)] = cmul(v7, twget(Tw, 7 * j));
    }
    // ---------- stage 2 (stride 8 within 64-blocks) ----------
    {
        const int b = lane6 >> 3, jp = lane6 & 7;
        const int sw = ((9 * b) & 63) ^ fx, bb = fbase + 64 * b;
        float2 v0 = Zc[bb + ((jp     ) ^ sw)];
        float2 v1 = Zc[bb + ((jp +  8) ^ sw)];
        float2 v2 = Zc[bb + ((jp + 16) ^ sw)];
        float2 v3 = Zc[bb + ((jp + 24) ^ sw)];
        float2 v4 = Zc[bb + ((jp + 32) ^ sw)];
        float2 v5 = Zc[bb + ((jp + 40) ^ sw)];
        float2 v6 = Zc[bb + ((jp + 48) ^ sw)];
        float2 v7 = Zc[bb + ((jp + 56) ^ sw)];
        radix8_inv(v0, v1, v2, v3, v4, v5, v6, v7);
        const int m1 = 8 * jp;
        Zc[bb + ((jp     ) ^ sw)] = v0;
        Zc[bb + ((jp +  8) ^ sw)] = cmul(v1, twget(Tw, m1));
        Zc[bb + ((jp + 16) ^ sw)] = cmul(v2, twget(Tw, 2 * m1));
        Zc[bb + ((jp + 24) ^ sw)] = cmul(v3, twget(Tw, 3 * m1));
        Zc[bb + ((jp + 32) ^ sw)] = cmul(v4, twget(Tw, 4 * m1));
        Zc[bb + ((jp + 40) ^ sw)] = cmul(v5, twget(Tw, 5 * m1));
        Zc[bb + ((jp + 48) ^ sw)] = cmul(v6, twget(Tw, 6 * m1));
        Zc[bb + ((jp + 56) ^ sw)] = cmul(v7, twget(Tw, 7 * m1));
    }
    // ---------- stage 3 (contiguous groups of 8, no twiddle) ----------
    {
        const int b = lane6 >> 3, g = lane6 & 7;
        const int sw = ((9 * b) & 63) ^ fx, bb = fbase + 64 * b, g8 = 8 * g;
        float2 v0 = Zc[bb + ((g8    ) ^ sw)];
        float2 v1 = Zc[bb + ((g8 + 1) ^ sw)];
        float2 v2 = Zc[bb + ((g8 + 2) ^ sw)];
        float2 v3 = Zc[bb + ((g8 + 3) ^ sw)];
        float2 v4 = Zc[bb + ((g8 + 4) ^ sw)];
        float2 v5 = Zc[bb + ((g8 + 5) ^ sw)];
        float2 v6 = Zc[bb + ((g8 + 6) ^ sw)];
        float2 v7 = Zc[bb + ((g8 + 7) ^ sw)];
        radix8_inv(v0, v1, v2, v3, v4, v5, v6, v7);
        Zc[bb + ((g8    ) ^ sw)] = v0;
        Zc[bb + ((g8 + 1) ^ sw)] = v1;
        Zc[bb + ((g8 + 2) ^ sw)] = v2;
        Zc[bb + ((g8 + 3) ^ sw)] = v3;
        Zc[bb + ((g8 + 4) ^ sw)] = v4;
        Zc[bb + ((g8 + 5) ^ sw)] = v5;
        Zc[bb + ((g8 + 6) ^ sw)] = v6;
        Zc[bb + ((g8 + 7) ^ sw)] = v7;
    }
    __syncthreads();

    // ---------- window + overlap-add: register accumulate -> direct global store ----------
    // Lean tap loop (R4): one Tw read per thread; (ce,se) rotated by exact quarter
    // turns (m steps by -128 = pi/2); opos(m) updated incrementally (k0,k1 invariant
    // across taps, only k2 -= 2; no borrow since m mod 64 is constant).
    {
        #pragma unroll
        for (int r = 0; r < 3; ++r) {
            int pi = tid + 512 * r;
            if (pi < NPAIR) {
                int slh = pi >> 7;                       // sl>>8 with sl=2*pi
                int tlo = max(slh - 3, 0), thi = min(slh, 7);
                int m0  = pi - (tlo << 7);               // in [0,512)
                int k0  = m0 & 7;
                int hi  = ((m0 >> 3) & 7) << 3;
                int k2v = m0 >> 6;
                int sw9 = (9 * k0) & 63;
                float2 t0c = Tw[m0 & 255];
                float sg = (m0 & 256) ? -1.f : 1.f;
                float ce = sg * t0c.x, se = sg * t0c.y;
                float ae = 0.f, ao = 0.f;
                int cb = (tlo << 9) + (k0 << 6);
                for (int fr = tlo; fr <= thi; ++fr) {
                    int low = ((hi | k2v) ^ sw9) ^ (fr << 1);
                    float2 zz = Zc[cb + low];
                    float co = ce * HR - se * HI;        // odd-sample window angle
                    ae += zz.x * (1.f - ce);
                    ao += zz.y * (1.f - co);
                    float nc = se; se = -ce; ce = nc;    // rotate -pi/2 (exact)
                    k2v -= 2; cb += 512;
                }
                ae *= 0.015625f; ao *= 0.015625f;        // sqrt(1024)*0.5/512/2 folded
                int s = S0 + (pi << 1);
                if (pi >= 384 && pi < 1024) {            // sl in [768,2048): group-exclusive
                    reinterpret_cast<float2*>(out)[(bc * LOUT + (s - 512)) >> 1] =
                        make_float2(ae, ao);
                } else if (s >= 512) {                   // seams + head-trim boundary
                    atomicAdd(&out[bc * LOUT + (s - 512)], ae);
                    atomicAdd(&out[bc * LOUT + (s - 511)], ao);
                }
            }
        }
    }
}

extern "C" void kernel_launch(void* const* d_in, const int* in_sizes, int n_in,
                              void* d_out, int out_size, void* d_ws, size_t ws_size,
                              hipStream_t stream) {
    const float2* x = (const float2*)d_in[0];
    float* out = (float*)d_out;
    (void)in_sizes; (void)n_in; (void)d_ws; (void)ws_size;

    hipMemsetAsync(d_out, 0, (size_t)out_size * sizeof(float), stream);

    dim3 grid(TFRAMES / NT_TILE, 64);   // 128 tiles x 64 (B*C) rows
    dim3 block(512);
    istft_kernel<<<grid, block, 0, stream>>>(x, out);
}

// Round 6
// 129.366 us; speedup vs baseline: 1.5546x; 1.0014x over previous
//
#include <hip/hip_runtime.h>
#include <math.h>

#define NFFT 1024
#define HOP 256
#define NFREQ 513
#define TFRAMES 1024
#define NT_TILE 8           /* 8 frames per block */
#define LOUT  262400        /* (1024 + 256*1023) - 512 */
#define NPAIR 1408          /* pairs per block: samples [0, 2816) */

__device__ __forceinline__ float2 cadd(float2 a, float2 b){ return make_float2(a.x+b.x, a.y+b.y); }
__device__ __forceinline__ float2 csub(float2 a, float2 b){ return make_float2(a.x-b.x, a.y-b.y); }
__device__ __forceinline__ float2 muli(float2 a){ return make_float2(-a.y, a.x); }   // * i
__device__ __forceinline__ float2 cmul(float2 a, float2 b){
    return make_float2(a.x*b.x - a.y*b.y, a.x*b.y + a.y*b.x);
}

// inverse-sign (e^{+2pi i/8}) radix-8 DFT on 8 named registers — no arrays, no spill
__device__ __forceinline__ void radix8_inv(float2& v0, float2& v1, float2& v2, float2& v3,
                                           float2& v4, float2& v5, float2& v6, float2& v7) {
    const float C = 0.70710678118654752f;
    float2 a0 = cadd(v0, v4), a1 = csub(v0, v4);
    float2 a2 = cadd(v2, v6), a3 = csub(v2, v6);
    float2 b0 = cadd(v1, v5), b1 = csub(v1, v5);
    float2 b2 = cadd(v3, v7), b3 = csub(v3, v7);
    float2 E0 = cadd(a0, a2), E2 = csub(a0, a2);
    float2 E1 = cadd(a1, muli(a3)), E3 = csub(a1, muli(a3));
    float2 O0 = cadd(b0, b2), O2 = csub(b0, b2);
    float2 O1 = cadd(b1, muli(b3)), O3 = csub(b1, muli(b3));
    float2 T1 = make_float2(C*(O1.x - O1.y),  C*(O1.x + O1.y));   // O1 * w8
    float2 T2 = muli(O2);                                          // O2 * w8^2
    float2 T3 = make_float2(-C*(O3.x + O3.y), C*(O3.x - O3.y));    // O3 * w8^3
    v0 = cadd(E0, O0); v4 = csub(E0, O0);
    v1 = cadd(E1, T1); v5 = csub(E1, T1);
    v2 = cadd(E2, T2); v6 = csub(E2, T2);
    v3 = cadd(E3, T3); v7 = csub(E3, T3);
}

// Tw[m] = e^{+2pi i m/512}, m in [0,512) via 256-entry table + sign fold
__device__ __forceinline__ float2 twget(const float2* Tw, int m) {
    float2 t = Tw[m & 255];
    float s = (m & 256) ? -1.f : 1.f;
    return make_float2(s * t.x, s * t.y);
}

// phase-1 storage position of natural index n (0..511), XOR-swizzled within 64-blocks
__device__ __forceinline__ int zpos(int n) {
    int blk = n >> 6;
    return blk * 64 + ((n & 63) ^ ((9 * blk) & 63));
}

// LDS: Zc 32768 + Tw 2048 = 34816 B -> 4 blocks/CU. Two barriers per block total:
// post-phase1 (covers Tw init + Zc pack) and post-stage3. Phase 1 is LDS-independent
// (register twiddles: one __sincosf + exact pi/8 rotation chain) so its global loads
// issue at kernel start, overlapped with the Tw table init.
// launch_bounds stays (512,4): tighter bounds force spills (R1: +450 MB scratch).
__global__ __launch_bounds__(512, 4) void istft_kernel(const float2* __restrict__ x,
                                                       float* __restrict__ out) {
    __shared__ float2 Zc[8 * 512];    // 32768 B
    __shared__ float2 Tw[256];        //  2048 B

    const int tid  = threadIdx.x;
    const int bc   = blockIdx.y;
    const int tile = blockIdx.x;
    const int t0   = tile * NT_TILE;
    const int S0   = t0 * HOP;

    // half-step rotation e^{+i pi/512} for odd bins / odd samples
    const float HR = 0.99998117528260111f, HI = 0.00613588464915448f;
    // pi/8 rotation for the phase-1 twiddle chain (kp steps of 64)
    const float C8 = 0.92387953251128676f, S8 = 0.38268343236508977f;

    // ---------- phase 1: global load + pack half-size spectrum (no Tw dependency) ----------
    {
        const int kg = tid >> 3, tt = tid & 7;
        const int tg = t0 + tt;
        const long baseIn = (long)bc * ((long)NFREQ * TFRAMES);
        const int wbase = tt << 9;
        const int fxw = tt << 1;
        float twr, twi;   // e^{+2pi i kp/1024}, kp = kg initially
        __sincosf((float)kg * 0.0061359231515425649f /* pi/512 */, &twi, &twr);
        #pragma unroll
        for (int i = 0; i < 5; ++i) {
            int kp = kg + 64 * i;
            if (kp <= 256) {
                float2 A = x[baseIn + (long)kp * TFRAMES + tg];
                float2 B = x[baseIn + (long)(512 - kp) * TFRAMES + tg];
                if (kp == 0) { A.y = 0.f; B.y = 0.f; }  // c2r drops DC/Nyquist imag
                float d2r = A.x - B.x, d2i = A.y + B.y;
                float o2r = twr * d2r - twi * d2i, o2i = twr * d2i + twi * d2r;
                float s2r = A.x + B.x, s2i = A.y - B.y;
                Zc[wbase + (zpos(kp) ^ fxw)] = make_float2(0.5f * (s2r - o2i), 0.5f * (s2i + o2r));
                if (kp >= 1 && kp <= 255)
                    Zc[wbase + (zpos(512 - kp) ^ fxw)] = make_float2(0.5f * (s2r + o2i), 0.5f * (o2r - s2i));
            }
            float nr = twr * C8 - twi * S8;   // rotate +pi/8 (kp += 64)
            twi = twr * S8 + twi * C8; twr = nr;
        }
    }
    // Tw table init (overlaps phase-1 loads; consumed only after the barrier)
    if (tid < 256) {
        float s, c;
        __sincosf((float)tid * (6.283185307179586f / 512.f), &s, &c);
        Tw[tid] = make_float2(c, s);
    }
    __syncthreads();

    const int f     = tid >> 6;      // wave-private frame (0..7)
    const int lane6 = tid & 63;
    const int fbase = f << 9;
    const int fx    = f << 1;        // per-frame bank swizzle (replaces stride pad)

    // ---------- radix-8 DIF stage 1 (stride 64) — wave-private, no barriers ----------
    {
        const int j = lane6, jx = lane6 ^ fx, zb = fbase;
        float2 v0 = Zc[zb +       (jx ^  0)];
        float2 v1 = Zc[zb +  64 + (jx ^  9)];
        float2 v2 = Zc[zb + 128 + (jx ^ 18)];
        float2 v3 = Zc[zb + 192 + (jx ^ 27)];
        float2 v4 = Zc[zb + 256 + (jx ^ 36)];
        float2 v5 = Zc[zb + 320 + (jx ^ 45)];
        float2 v6 = Zc[zb + 384 + (jx ^ 54)];
        float2 v7 = Zc[zb + 448 + (jx ^ 63)];
        radix8_inv(v0, v1, v2, v3, v4, v5, v6, v7);
        Zc[zb +       (jx ^  0)] = v0;
        Zc[zb +  64 + (jx ^  9)] = cmul(v1, twget(Tw, j));
        Zc[zb + 128 + (jx ^ 18)] = cmul(v2, twget(Tw, 2 * j));
        Zc[zb + 192 + (jx ^ 27)] = cmul(v3, twget(Tw, 3 * j));
        Zc[zb + 256 + (jx ^ 36)] = cmul(v4, twget(Tw, 4 * j));
        Zc[zb + 320 + (jx ^ 45)] = cmul(v5, twget(Tw, 5 * j));
        Zc[zb + 384 + (jx ^ 54)] = cmul(v6, twget(Tw, 6 * j));
        Zc[zb + 448 + (jx ^ 63)] = cmul(v7, twget(Tw, 7 * j));
    }
    // ---------- stage 2 (stride 8 within 64-blocks) ----------
    {
        const int b = lane6 >> 3, jp = lane6 & 7;
        const int sw = ((9 * b) & 63) ^ fx, bb = fbase + 64 * b;
        float2 v0 = Zc[bb + ((jp     ) ^ sw)];
        float2 v1 = Zc[bb + ((jp +  8) ^ sw)];
        float2 v2 = Zc[bb + ((jp + 16) ^ sw)];
        float2 v3 = Zc[bb + ((jp + 24) ^ sw)];
        float2 v4 = Zc[bb + ((jp + 32) ^ sw)];
        float2 v5 = Zc[bb + ((jp + 40) ^ sw)];
        float2 v6 = Zc[bb + ((jp + 48) ^ sw)];
        float2 v7 = Zc[bb + ((jp + 56) ^ sw)];
        radix8_inv(v0, v1, v2, v3, v4, v5, v6, v7);
        const int m1 = 8 * jp;
        Zc[bb + ((jp     ) ^ sw)] = v0;
        Zc[bb + ((jp +  8) ^ sw)] = cmul(v1, twget(Tw, m1));
        Zc[bb + ((jp + 16) ^ sw)] = cmul(v2, twget(Tw, 2 * m1));
        Zc[bb + ((jp + 24) ^ sw)] = cmul(v3, twget(Tw, 3 * m1));
        Zc[bb + ((jp + 32) ^ sw)] = cmul(v4, twget(Tw, 4 * m1));
        Zc[bb + ((jp + 40) ^ sw)] = cmul(v5, twget(Tw, 5 * m1));
        Zc[bb + ((jp + 48) ^ sw)] = cmul(v6, twget(Tw, 6 * m1));
        Zc[bb + ((jp + 56) ^ sw)] = cmul(v7, twget(Tw, 7 * m1));
    }
    // ---------- stage 3 (contiguous groups of 8, no twiddle) ----------
    {
        const int b = lane6 >> 3, g = lane6 & 7;
        const int sw = ((9 * b) & 63) ^ fx, bb = fbase + 64 * b, g8 = 8 * g;
        float2 v0 = Zc[bb + ((g8    ) ^ sw)];
        float2 v1 = Zc[bb + ((g8 + 1) ^ sw)];
        float2 v2 = Zc[bb + ((g8 + 2) ^ sw)];
        float2 v3 = Zc[bb + ((g8 + 3) ^ sw)];
        float2 v4 = Zc[bb + ((g8 + 4) ^ sw)];
        float2 v5 = Zc[bb + ((g8 + 5) ^ sw)];
        float2 v6 = Zc[bb + ((g8 + 6) ^ sw)];
        float2 v7 = Zc[bb + ((g8 + 7) ^ sw)];
        radix8_inv(v0, v1, v2, v3, v4, v5, v6, v7);
        Zc[bb + ((g8    ) ^ sw)] = v0;
        Zc[bb + ((g8 + 1) ^ sw)] = v1;
        Zc[bb + ((g8 + 2) ^ sw)] = v2;
        Zc[bb + ((g8 + 3) ^ sw)] = v3;
        Zc[bb + ((g8 + 4) ^ sw)] = v4;
        Zc[bb + ((g8 + 5) ^ sw)] = v5;
        Zc[bb + ((g8 + 6) ^ sw)] = v6;
        Zc[bb + ((g8 + 7) ^ sw)] = v7;
    }
    __syncthreads();

    // ---------- window + overlap-add: 4 independent predicated taps ----------
    // Taps use exact quarter-turn sign permutations of one (ce,se) pair:
    // u=0:(ce,se) u=1:(se,-ce) u=2:(-ce,-se) u=3:(-se,ce) — no serial rotation
    // chain, so the 4 ds_read_b64 issue back-to-back and overlap latency.
    // opos(m) incremental: k0,hi invariant across taps; k2 -= 2 (no borrow).
    {
        #pragma unroll
        for (int r = 0; r < 3; ++r) {
            int pi = tid + 512 * r;
            if (pi < NPAIR) {
                int slh = pi >> 7;                       // sl>>8 with sl=2*pi
                int tlo = max(slh - 3, 0), thi = min(slh, 7);
                int nt  = thi - tlo;                     // 0..3
                int m0  = pi - (tlo << 7);               // in [0,512)
                int k0  = m0 & 7;
                int hi  = ((m0 >> 3) & 7) << 3;
                int k2v = m0 >> 6;
                int sw9 = (9 * k0) & 63;
                float2 t0c = Tw[m0 & 255];
                float sg = (m0 & 256) ? -1.f : 1.f;
                float ce = sg * t0c.x, se = sg * t0c.y;
                float ae = 0.f, ao = 0.f;
                int cb = (tlo << 9) + (k0 << 6);
                #pragma unroll
                for (int u = 0; u < 4; ++u) {
                    if (u <= nt) {
                        int low = ((hi | (k2v - 2 * u)) ^ sw9) ^ ((tlo + u) << 1);
                        float2 zz = Zc[cb + (u << 9) + low];
                        float cu = (u == 0) ? ce : (u == 1) ? se : (u == 2) ? -ce : -se;
                        float su = (u == 0) ? se : (u == 1) ? -ce : (u == 2) ? -se : ce;
                        float cou = cu * HR - su * HI;   // odd-sample window angle
                        ae += zz.x * (1.f - cu);
                        ao += zz.y * (1.f - cou);
                    }
                }
                ae *= 0.015625f; ao *= 0.015625f;        // sqrt(1024)*0.5/512/2 folded
                int s = S0 + (pi << 1);
                int o = bc * LOUT + (s - 512);
                if (pi >= 384 && pi < 1024) {            // sl in [768,2048): group-exclusive
                    reinterpret_cast<float2*>(out)[o >> 1] = make_float2(ae, ao);
                } else if (s >= 512) {                   // seams + head-trim boundary
                    atomicAdd(&out[o],     ae);
                    atomicAdd(&out[o + 1], ao);
                }
            }
        }
    }
}

extern "C" void kernel_launch(void* const* d_in, const int* in_sizes, int n_in,
                              void* d_out, int out_size, void* d_ws, size_t ws_size,
                              hipStream_t stream) {
    const float2* x = (const float2*)d_in[0];
    float* out = (float*)d_out;
    (void)in_sizes; (void)n_in; (void)d_ws; (void)ws_size;

    hipMemsetAsync(d_out, 0, (size_t)out_size * sizeof(float), stream);

    dim3 grid(TFRAMES / NT_TILE, 64);   // 128 tiles x 64 (B*C) rows
    dim3 block(512);
    istft_kernel<<<grid, block, 0, stream>>>(x, out);
}

// Round 8
// 128.935 us; speedup vs baseline: 1.5598x; 1.0033x over previous
//
#include <hip/hip_runtime.h>
#include <math.h>

#define NFFT 1024
#define HOP 256
#define NFREQ 513
#define TFRAMES 1024
#define NT_TILE 8           /* 8 frames per block */
#define LOUT  262400        /* (1024 + 256*1023) - 512 */
#define NPAIR 1408          /* pairs per block: samples [0, 2816) */

__device__ __forceinline__ float2 cadd(float2 a, float2 b){ return make_float2(a.x+b.x, a.y+b.y); }
__device__ __forceinline__ float2 csub(float2 a, float2 b){ return make_float2(a.x-b.x, a.y-b.y); }
__device__ __forceinline__ float2 muli(float2 a){ return make_float2(-a.y, a.x); }   // * i
__device__ __forceinline__ float2 cmul(float2 a, float2 b){
    return make_float2(a.x*b.x - a.y*b.y, a.x*b.y + a.y*b.x);
}

// inverse-sign (e^{+2pi i/8}) radix-8 DFT on 8 named registers — no arrays, no spill
__device__ __forceinline__ void radix8_inv(float2& v0, float2& v1, float2& v2, float2& v3,
                                           float2& v4, float2& v5, float2& v6, float2& v7) {
    const float C = 0.70710678118654752f;
    float2 a0 = cadd(v0, v4), a1 = csub(v0, v4);
    float2 a2 = cadd(v2, v6), a3 = csub(v2, v6);
    float2 b0 = cadd(v1, v5), b1 = csub(v1, v5);
    float2 b2 = cadd(v3, v7), b3 = csub(v3, v7);
    float2 E0 = cadd(a0, a2), E2 = csub(a0, a2);
    float2 E1 = cadd(a1, muli(a3)), E3 = csub(a1, muli(a3));
    float2 O0 = cadd(b0, b2), O2 = csub(b0, b2);
    float2 O1 = cadd(b1, muli(b3)), O3 = csub(b1, muli(b3));
    float2 T1 = make_float2(C*(O1.x - O1.y),  C*(O1.x + O1.y));   // O1 * w8
    float2 T2 = muli(O2);                                          // O2 * w8^2
    float2 T3 = make_float2(-C*(O3.x + O3.y), C*(O3.x - O3.y));    // O3 * w8^3
    v0 = cadd(E0, O0); v4 = csub(E0, O0);
    v1 = cadd(E1, T1); v5 = csub(E1, T1);
    v2 = cadd(E2, T2); v6 = csub(E2, T2);
    v3 = cadd(E3, T3); v7 = csub(E3, T3);
}

// phase-1 storage position of natural index n (0..511), XOR-swizzled within 64-blocks
__device__ __forceinline__ int zpos(int n) {
    int blk = n >> 6;
    return blk * 64 + ((n & 63) ^ ((9 * blk) & 63));
}

// LDS: Zc 32768 + Tw 4096 = 36864 B -> 4 blocks/CU (147456 <= 163840).
// Tw is a FULL 512-entry table (e^{+2pi i m/512}): stage-twiddle indices are
// q*j <= 441 and q*8jp <= 392, so no &255 mask and no sign-fold anywhere.
// launch_bounds stays (512,4): tighter bounds force spills (R1: +450 MB scratch).
__global__ __launch_bounds__(512, 4) void istft_kernel(const float2* __restrict__ x,
                                                       float* __restrict__ out) {
    __shared__ float2 Zc[8 * 512];    // 32768 B
    __shared__ float2 Tw[512];        //  4096 B

    const int tid  = threadIdx.x;
    const int bc   = blockIdx.y;
    const int tile = blockIdx.x;
    const int t0   = tile * NT_TILE;
    const int S0   = t0 * HOP;

    // half-step rotation e^{+i pi/512} for odd bins / odd samples
    const float HR = 0.99998117528260111f, HI = 0.00613588464915448f;
    // pi/8 rotation for the phase-1 twiddle chain (kp steps of 64)
    const float C8 = 0.92387953251128676f, S8 = 0.38268343236508977f;

    // ---------- phase 1: global load + pack half-size spectrum (no Tw dependency) ----------
    {
        const int kg = tid >> 3, tt = tid & 7;
        const int tg = t0 + tt;
        const long baseIn = (long)bc * ((long)NFREQ * TFRAMES);
        const int wbase = tt << 9;
        const int fxw = tt << 1;
        float twr, twi;   // 0.5 * e^{+2pi i kp/1024}, kp = kg initially (0.5 pack factor folded)
        __sincosf((float)kg * 0.0061359231515425649f /* pi/512 */, &twi, &twr);
        twr *= 0.5f; twi *= 0.5f;
        #pragma unroll
        for (int i = 0; i < 5; ++i) {
            int kp = kg + 64 * i;
            if (kp <= 256) {
                float2 A = x[baseIn + (long)kp * TFRAMES + tg];
                float2 B = x[baseIn + (long)(512 - kp) * TFRAMES + tg];
                if (kp == 0) { A.y = 0.f; B.y = 0.f; }  // c2r drops DC/Nyquist imag
                float d2r = A.x - B.x, d2i = A.y + B.y;
                float o2r = twr * d2r - twi * d2i, o2i = twr * d2i + twi * d2r;  // x0.5 folded
                float s2r = 0.5f * (A.x + B.x), s2i = 0.5f * (A.y - B.y);
                Zc[wbase + (zpos(kp) ^ fxw)] = make_float2(s2r - o2i, s2i + o2r);
                if (kp >= 1 && kp <= 255)
                    Zc[wbase + (zpos(512 - kp) ^ fxw)] = make_float2(s2r + o2i, o2r - s2i);
            }
            float nr = twr * C8 - twi * S8;   // rotate +pi/8 (kp += 64), preserves 0.5 scale
            twi = twr * S8 + twi * C8; twr = nr;
        }
    }
    // Tw table init (overlaps phase-1 loads; consumed only after the barrier)
    {
        float s, c;
        __sincosf((float)tid * (6.283185307179586f / 512.f), &s, &c);
        Tw[tid] = make_float2(c, s);
    }
    __syncthreads();

    const int f     = tid >> 6;      // wave-private frame (0..7)
    const int lane6 = tid & 63;
    const int fbase = f << 9;
    const int fx    = f << 1;        // per-frame bank swizzle (replaces stride pad)

    // ---------- radix-8 DIF stage 1 (stride 64) — wave-private, no barriers ----------
    {
        const int j = lane6, jx = lane6 ^ fx, zb = fbase;
        float2 v0 = Zc[zb +       (jx ^  0)];
        float2 v1 = Zc[zb +  64 + (jx ^  9)];
        float2 v2 = Zc[zb + 128 + (jx ^ 18)];
        float2 v3 = Zc[zb + 192 + (jx ^ 27)];
        float2 v4 = Zc[zb + 256 + (jx ^ 36)];
        float2 v5 = Zc[zb + 320 + (jx ^ 45)];
        float2 v6 = Zc[zb + 384 + (jx ^ 54)];
        float2 v7 = Zc[zb + 448 + (jx ^ 63)];
        radix8_inv(v0, v1, v2, v3, v4, v5, v6, v7);
        Zc[zb +       (jx ^  0)] = v0;
        Zc[zb +  64 + (jx ^  9)] = cmul(v1, Tw[j]);
        Zc[zb + 128 + (jx ^ 18)] = cmul(v2, Tw[2 * j]);
        Zc[zb + 192 + (jx ^ 27)] = cmul(v3, Tw[3 * j]);
        Zc[zb + 256 + (jx ^ 36)] = cmul(v4, Tw[4 * j]);
        Zc[zb + 320 + (jx ^ 45)] = cmul(v5, Tw[5 * j]);
        Zc[zb + 384 + (jx ^ 54)] = cmul(v6, Tw[6 * j]);
        Zc[zb + 448 + (jx ^ 63)] = cmul(v7, Tw[7 * j]);
    }
    // ---------- stage 2 (stride 8 within 64-blocks) ----------
    {
        const int b = lane6 >> 3, jp = lane6 & 7;
        const int sw = ((9 * b) & 63) ^ fx, bb = fbase + 64 * b;
        float2 v0 = Zc[bb + ((jp     ) ^ sw)];
        float2 v1 = Zc[bb + ((jp +  8) ^ sw)];
        float2 v2 = Zc[bb + ((jp + 16) ^ sw)];
        float2 v3 = Zc[bb + ((jp + 24) ^ sw)];
        float2 v4 = Zc[bb + ((jp + 32) ^ sw)];
        float2 v5 = Zc[bb + ((jp + 40) ^ sw)];
        float2 v6 = Zc[bb + ((jp + 48) ^ sw)];
        float2 v7 = Zc[bb + ((jp + 56) ^ sw)];
        radix8_inv(v0, v1, v2, v3, v4, v5, v6, v7);
        const int m1 = 8 * jp;
        Zc[bb + ((jp     ) ^ sw)] = v0;
        Zc[bb + ((jp +  8) ^ sw)] = cmul(v1, Tw[m1]);
        Zc[bb + ((jp + 16) ^ sw)] = cmul(v2, Tw[2 * m1]);
        Zc[bb + ((jp + 24) ^ sw)] = cmul(v3, Tw[3 * m1]);
        Zc[bb + ((jp + 32) ^ sw)] = cmul(v4, Tw[4 * m1]);
        Zc[bb + ((jp + 40) ^ sw)] = cmul(v5, Tw[5 * m1]);
        Zc[bb + ((jp + 48) ^ sw)] = cmul(v6, Tw[6 * m1]);
        Zc[bb + ((jp + 56) ^ sw)] = cmul(v7, Tw[7 * m1]);
    }
    // ---------- stage 3 (contiguous groups of 8, no twiddle) ----------
    {
        const int b = lane6 >> 3, g = lane6 & 7;
        const int sw = ((9 * b) & 63) ^ fx, bb = fbase + 64 * b, g8 = 8 * g;
        float2 v0 = Zc[bb + ((g8    ) ^ sw)];
        float2 v1 = Zc[bb + ((g8 + 1) ^ sw)];
        float2 v2 = Zc[bb + ((g8 + 2) ^ sw)];
        float2 v3 = Zc[bb + ((g8 + 3) ^ sw)];
        float2 v4 = Zc[bb + ((g8 + 4) ^ sw)];
        float2 v5 = Zc[bb + ((g8 + 5) ^ sw)];
        float2 v6 = Zc[bb + ((g8 + 6) ^ sw)];
        float2 v7 = Zc[bb + ((g8 + 7) ^ sw)];
        radix8_inv(v0, v1, v2, v3, v4, v5, v6, v7);
        Zc[bb + ((g8    ) ^ sw)] = v0;
        Zc[bb + ((g8 + 1) ^ sw)] = v1;
        Zc[bb + ((g8 + 2) ^ sw)] = v2;
        Zc[bb + ((g8 + 3) ^ sw)] = v3;
        Zc[bb + ((g8 + 4) ^ sw)] = v4;
        Zc[bb + ((g8 + 5) ^ sw)] = v5;
        Zc[bb + ((g8 + 6) ^ sw)] = v6;
        Zc[bb + ((g8 + 7) ^ sw)] = v7;
    }
    __syncthreads();

    // ---------- window + overlap-add: three exact-trip specialized loops ----------
    // r0 head (taps 1-4, wave-uniform), r1 interior (static 4 taps, no predicates),
    // r2 tail (taps 1-3, wave-uniform) REUSING r1's full setup: same m0 since
    // m0 = pi+512 - (tlo+4)*128 = pi - tlo*128. Quarter-turn taps (m -= 128 = -pi/2).

    // r0: pi = tid in [0,512), frames 0..slh
    {
        const int pi = tid;
        const int slh = pi >> 7;                 // 0..3, wave-uniform
        const int k0 = pi & 7;
        const int hi = ((pi >> 3) & 7) << 3;
        const int k2v = pi >> 6;
        const int sw9 = (9 * k0) & 63;
        float2 tc = Tw[pi];
        float ce = tc.x, se = tc.y;
        float ae = 0.f, ao = 0.f;
        const int cb = k0 << 6;                  // tlo = 0
        #pragma unroll 4
        for (int u = 0; u <= slh; ++u) {
            int low = ((hi | (k2v - 2 * u)) ^ sw9) ^ (u << 1);
            float2 zz = Zc[cb + (u << 9) + low];
            float cou = ce * HR - se * HI;       // odd-sample window angle
            ae += zz.x * (1.f - ce);
            ao += zz.y * (1.f - cou);
            float nc = se; se = -ce; ce = nc;    // rotate -pi/2 (exact)
        }
        ae *= 0.015625f; ao *= 0.015625f;        // sqrt(1024)*0.5/512/2 folded
        int s = S0 + (pi << 1);
        int o = bc * LOUT + (s - 512);
        if (pi >= 384) {                         // sl in [768,1024): group-exclusive
            reinterpret_cast<float2*>(out)[o >> 1] = make_float2(ae, ao);
        } else if (s >= 512) {                   // head seam / head-trim boundary
            atomicAdd(&out[o],     ae);
            atomicAdd(&out[o + 1], ao);
        }
    }

    // r1 + r2 (shared setup)
    {
        const int pi = tid + 512;                // [512,1024)
        const int slh = pi >> 7;                 // 4..7
        const int tlo = slh - 3;                 // 1..4
        const int m0 = pi - (tlo << 7);          // in [384,512)
        const int k0 = m0 & 7;
        const int hi = ((m0 >> 3) & 7) << 3;
        const int k2v = m0 >> 6;
        const int sw9 = (9 * k0) & 63;
        float2 tc = Tw[m0];
        const float ce = tc.x, se = tc.y;
        const int cb = (tlo << 9) + (k0 << 6);

        // r1: always 4 taps, static sign permutations, no predicates
        {
            float ae = 0.f, ao = 0.f;
            #pragma unroll
            for (int u = 0; u < 4; ++u) {
                int low = ((hi | (k2v - 2 * u)) ^ sw9) ^ ((tlo + u) << 1);
                float2 zz = Zc[cb + (u << 9) + low];
                float cu = (u == 0) ? ce : (u == 1) ? se : (u == 2) ? -ce : -se;
                float su = (u == 0) ? se : (u == 1) ? -ce : (u == 2) ? -se : ce;
                float cou = cu * HR - su * HI;
                ae += zz.x * (1.f - cu);
                ao += zz.y * (1.f - cou);
            }
            ae *= 0.015625f; ao *= 0.015625f;
            int s = S0 + (pi << 1);
            reinterpret_cast<float2*>(out)[(bc * LOUT + (s - 512)) >> 1] = make_float2(ae, ao);
        }

        // r2: pi2 = pi + 512 in [1024,1408), frames tlo+4..7 (1-3 taps, wave-uniform)
        if (tid < 384) {
            const int ntap = 4 - tlo;            // 3,2,1
            float ce2 = ce, se2 = se;
            float ae = 0.f, ao = 0.f;
            const int cb2 = cb + (4 << 9);
            #pragma unroll 3
            for (int u = 0; u < ntap; ++u) {
                int low = ((hi | (k2v - 2 * u)) ^ sw9) ^ ((tlo + 4 + u) << 1);
                float2 zz = Zc[cb2 + (u << 9) + low];
                float cou = ce2 * HR - se2 * HI;
                ae += zz.x * (1.f - ce2);
                ao += zz.y * (1.f - cou);
                float nc = se2; se2 = -ce2; ce2 = nc;
            }
            ae *= 0.015625f; ao *= 0.015625f;
            int s = S0 + ((pi + 512) << 1);      // >= 2048, always >= 512
            int o = bc * LOUT + (s - 512);
            atomicAdd(&out[o],     ae);          // tail seam with next tile
            atomicAdd(&out[o + 1], ao);
        }
    }
}

extern "C" void kernel_launch(void* const* d_in, const int* in_sizes, int n_in,
                              void* d_out, int out_size, void* d_ws, size_t ws_size,
                              hipStream_t stream) {
    const float2* x = (const float2*)d_in[0];
    float* out = (float*)d_out;
    (void)in_sizes; (void)n_in; (void)d_ws; (void)ws_size;

    hipMemsetAsync(d_out, 0, (size_t)out_size * sizeof(float), stream);

    dim3 grid(TFRAMES / NT_TILE, 64);   // 128 tiles x 64 (B*C) rows
    dim3 block(512);
    istft_kernel<<<grid, block, 0, stream>>>(x, out);
}

// Round 9
// 128.836 us; speedup vs baseline: 1.5610x; 1.0008x over previous
//
#include <hip/hip_runtime.h>
#include <math.h>

#define NFFT 1024
#define HOP 256
#define NFREQ 513
#define TFRAMES 1024
#define NT_TILE 8           /* 8 frames per block */
#define LOUT  262400        /* (1024 + 256*1023) - 512 */
#define NPAIR 1408          /* pairs per block: samples [0, 2816) */

__device__ __forceinline__ float2 cadd(float2 a, float2 b){ return make_float2(a.x+b.x, a.y+b.y); }
__device__ __forceinline__ float2 csub(float2 a, float2 b){ return make_float2(a.x-b.x, a.y-b.y); }
__device__ __forceinline__ float2 muli(float2 a){ return make_float2(-a.y, a.x); }   // * i
__device__ __forceinline__ float2 cmul(float2 a, float2 b){
    return make_float2(a.x*b.x - a.y*b.y, a.x*b.y + a.y*b.x);
}

// inverse-sign (e^{+2pi i/8}) radix-8 DFT on 8 named registers — no arrays, no spill
__device__ __forceinline__ void radix8_inv(float2& v0, float2& v1, float2& v2, float2& v3,
                                           float2& v4, float2& v5, float2& v6, float2& v7) {
    const float C = 0.70710678118654752f;
    float2 a0 = cadd(v0, v4), a1 = csub(v0, v4);
    float2 a2 = cadd(v2, v6), a3 = csub(v2, v6);
    float2 b0 = cadd(v1, v5), b1 = csub(v1, v5);
    float2 b2 = cadd(v3, v7), b3 = csub(v3, v7);
    float2 E0 = cadd(a0, a2), E2 = csub(a0, a2);
    float2 E1 = cadd(a1, muli(a3)), E3 = csub(a1, muli(a3));
    float2 O0 = cadd(b0, b2), O2 = csub(b0, b2);
    float2 O1 = cadd(b1, muli(b3)), O3 = csub(b1, muli(b3));
    float2 T1 = make_float2(C*(O1.x - O1.y),  C*(O1.x + O1.y));   // O1 * w8
    float2 T2 = muli(O2);                                          // O2 * w8^2
    float2 T3 = make_float2(-C*(O3.x + O3.y), C*(O3.x - O3.y));    // O3 * w8^3
    v0 = cadd(E0, O0); v4 = csub(E0, O0);
    v1 = cadd(E1, T1); v5 = csub(E1, T1);
    v2 = cadd(E2, T2); v6 = csub(E2, T2);
    v3 = cadd(E3, T3); v7 = csub(E3, T3);
}

// phase-1 storage position of natural index n (0..511), XOR-swizzled within 64-blocks
__device__ __forceinline__ int zpos(int n) {
    int blk = n >> 6;
    return blk * 64 + ((n & 63) ^ ((9 * blk) & 63));
}

// LDS: Zc only, 32768 B. NO twiddle table: every stage needs only POWERS of one
// per-thread base twiddle -> one __sincosf (TRANS pipe) + squaring chain in regs.
// This removes ~17 LDS ops/thread including ALL the bank-conflicted ones
// (Tw[2j]/Tw[4j] were 16/32-way; all stage-2 Tw[8jp*q] reads hit bank 0).
// launch_bounds stays (512,4): tighter bounds force spills (R1: +450 MB scratch).
__global__ __launch_bounds__(512, 4) void istft_kernel(const float2* __restrict__ x,
                                                       float* __restrict__ out) {
    __shared__ float2 Zc[8 * 512];    // 32768 B

    const int tid  = threadIdx.x;
    const int bc   = blockIdx.y;
    const int tile = blockIdx.x;
    const int t0   = tile * NT_TILE;
    const int S0   = t0 * HOP;

    // half-step rotation e^{+i pi/512} for odd bins / odd samples
    const float HR = 0.99998117528260111f, HI = 0.00613588464915448f;
    // pi/8 rotation for the phase-1 twiddle chain (kp steps of 64)
    const float C8 = 0.92387953251128676f, S8 = 0.38268343236508977f;
    const float A512 = 0.012271846303085130f;   // 2*pi/512

    // ---------- phase 1: global load + pack half-size spectrum ----------
    {
        const int kg = tid >> 3, tt = tid & 7;
        const int tg = t0 + tt;
        const long baseIn = (long)bc * ((long)NFREQ * TFRAMES);
        const int wbase = tt << 9;
        const int fxw = tt << 1;
        float twr, twi;   // 0.5 * e^{+2pi i kp/1024}, kp = kg initially (0.5 pack factor folded)
        __sincosf((float)kg * 0.0061359231515425649f /* pi/512 */, &twi, &twr);
        twr *= 0.5f; twi *= 0.5f;
        #pragma unroll
        for (int i = 0; i < 5; ++i) {
            int kp = kg + 64 * i;
            if (kp <= 256) {
                float2 A = x[baseIn + (long)kp * TFRAMES + tg];
                float2 B = x[baseIn + (long)(512 - kp) * TFRAMES + tg];
                if (kp == 0) { A.y = 0.f; B.y = 0.f; }  // c2r drops DC/Nyquist imag
                float d2r = A.x - B.x, d2i = A.y + B.y;
                float o2r = twr * d2r - twi * d2i, o2i = twr * d2i + twi * d2r;  // x0.5 folded
                float s2r = 0.5f * (A.x + B.x), s2i = 0.5f * (A.y - B.y);
                Zc[wbase + (zpos(kp) ^ fxw)] = make_float2(s2r - o2i, s2i + o2r);
                if (kp >= 1 && kp <= 255)
                    Zc[wbase + (zpos(512 - kp) ^ fxw)] = make_float2(s2r + o2i, o2r - s2i);
            }
            float nr = twr * C8 - twi * S8;   // rotate +pi/8 (kp += 64), preserves 0.5 scale
            twi = twr * S8 + twi * C8; twr = nr;
        }
    }
    __syncthreads();

    const int f     = tid >> 6;      // wave-private frame (0..7)
    const int lane6 = tid & 63;
    const int fbase = f << 9;
    const int fx    = f << 1;        // per-frame bank swizzle (replaces stride pad)

    // ---------- radix-8 DIF stage 1 (stride 64) — wave-private, no barriers ----------
    {
        const int j = lane6, jx = lane6 ^ fx, zb = fbase;
        float2 v0 = Zc[zb +       (jx ^  0)];
        float2 v1 = Zc[zb +  64 + (jx ^  9)];
        float2 v2 = Zc[zb + 128 + (jx ^ 18)];
        float2 v3 = Zc[zb + 192 + (jx ^ 27)];
        float2 v4 = Zc[zb + 256 + (jx ^ 36)];
        float2 v5 = Zc[zb + 320 + (jx ^ 45)];
        float2 v6 = Zc[zb + 384 + (jx ^ 54)];
        float2 v7 = Zc[zb + 448 + (jx ^ 63)];
        radix8_inv(v0, v1, v2, v3, v4, v5, v6, v7);
        // register twiddles: w = e^{+2pi i j/512}; powers by squaring (depth <= 3)
        float sw_, cw_;
        __sincosf((float)j * A512, &sw_, &cw_);
        float2 w1 = make_float2(cw_, sw_);
        float2 w2 = cmul(w1, w1);
        float2 w3 = cmul(w2, w1);
        float2 w4 = cmul(w2, w2);
        float2 w5 = cmul(w3, w2);
        float2 w6 = cmul(w3, w3);
        float2 w7 = cmul(w4, w3);
        Zc[zb +       (jx ^  0)] = v0;
        Zc[zb +  64 + (jx ^  9)] = cmul(v1, w1);
        Zc[zb + 128 + (jx ^ 18)] = cmul(v2, w2);
        Zc[zb + 192 + (jx ^ 27)] = cmul(v3, w3);
        Zc[zb + 256 + (jx ^ 36)] = cmul(v4, w4);
        Zc[zb + 320 + (jx ^ 45)] = cmul(v5, w5);
        Zc[zb + 384 + (jx ^ 54)] = cmul(v6, w6);
        Zc[zb + 448 + (jx ^ 63)] = cmul(v7, w7);
    }
    // ---------- stage 2 (stride 8 within 64-blocks) ----------
    {
        const int b = lane6 >> 3, jp = lane6 & 7;
        const int sw = ((9 * b) & 63) ^ fx, bb = fbase + 64 * b;
        float2 v0 = Zc[bb + ((jp     ) ^ sw)];
        float2 v1 = Zc[bb + ((jp +  8) ^ sw)];
        float2 v2 = Zc[bb + ((jp + 16) ^ sw)];
        float2 v3 = Zc[bb + ((jp + 24) ^ sw)];
        float2 v4 = Zc[bb + ((jp + 32) ^ sw)];
        float2 v5 = Zc[bb + ((jp + 40) ^ sw)];
        float2 v6 = Zc[bb + ((jp + 48) ^ sw)];
        float2 v7 = Zc[bb + ((jp + 56) ^ sw)];
        radix8_inv(v0, v1, v2, v3, v4, v5, v6, v7);
        // register twiddles: w = e^{+2pi i jp/64}
        float sw_, cw_;
        __sincosf((float)jp * 0.098174770424681039f /* 2pi/64 */, &sw_, &cw_);
        float2 w1 = make_float2(cw_, sw_);
        float2 w2 = cmul(w1, w1);
        float2 w3 = cmul(w2, w1);
        float2 w4 = cmul(w2, w2);
        float2 w5 = cmul(w3, w2);
        float2 w6 = cmul(w3, w3);
        float2 w7 = cmul(w4, w3);
        Zc[bb + ((jp     ) ^ sw)] = v0;
        Zc[bb + ((jp +  8) ^ sw)] = cmul(v1, w1);
        Zc[bb + ((jp + 16) ^ sw)] = cmul(v2, w2);
        Zc[bb + ((jp + 24) ^ sw)] = cmul(v3, w3);
        Zc[bb + ((jp + 32) ^ sw)] = cmul(v4, w4);
        Zc[bb + ((jp + 40) ^ sw)] = cmul(v5, w5);
        Zc[bb + ((jp + 48) ^ sw)] = cmul(v6, w6);
        Zc[bb + ((jp + 56) ^ sw)] = cmul(v7, w7);
    }
    // ---------- stage 3 (contiguous groups of 8, no twiddle) ----------
    {
        const int b = lane6 >> 3, g = lane6 & 7;
        const int sw = ((9 * b) & 63) ^ fx, bb = fbase + 64 * b, g8 = 8 * g;
        float2 v0 = Zc[bb + ((g8    ) ^ sw)];
        float2 v1 = Zc[bb + ((g8 + 1) ^ sw)];
        float2 v2 = Zc[bb + ((g8 + 2) ^ sw)];
        float2 v3 = Zc[bb + ((g8 + 3) ^ sw)];
        float2 v4 = Zc[bb + ((g8 + 4) ^ sw)];
        float2 v5 = Zc[bb + ((g8 + 5) ^ sw)];
        float2 v6 = Zc[bb + ((g8 + 6) ^ sw)];
        float2 v7 = Zc[bb + ((g8 + 7) ^ sw)];
        radix8_inv(v0, v1, v2, v3, v4, v5, v6, v7);
        Zc[bb + ((g8    ) ^ sw)] = v0;
        Zc[bb + ((g8 + 1) ^ sw)] = v1;
        Zc[bb + ((g8 + 2) ^ sw)] = v2;
        Zc[bb + ((g8 + 3) ^ sw)] = v3;
        Zc[bb + ((g8 + 4) ^ sw)] = v4;
        Zc[bb + ((g8 + 5) ^ sw)] = v5;
        Zc[bb + ((g8 + 6) ^ sw)] = v6;
        Zc[bb + ((g8 + 7) ^ sw)] = v7;
    }
    __syncthreads();

    // ---------- window + overlap-add: three exact-trip specialized loops ----------
    // r0 head (taps 1-4, wave-uniform), r1 interior (static 4 taps, no predicates),
    // r2 tail (taps 1-3, wave-uniform) REUSING r1's full setup: same m0 since
    // m0 = pi+512 - (tlo+4)*128 = pi - tlo*128. Quarter-turn taps (m -= 128 = -pi/2).

    // r0: pi = tid in [0,512), frames 0..slh
    {
        const int pi = tid;
        const int slh = pi >> 7;                 // 0..3, wave-uniform
        const int k0 = pi & 7;
        const int hi = ((pi >> 3) & 7) << 3;
        const int k2v = pi >> 6;
        const int sw9 = (9 * k0) & 63;
        float se, ce;
        __sincosf((float)pi * A512, &se, &ce);   // (cos, sin) of 2pi*pi/512
        float ae = 0.f, ao = 0.f;
        const int cb = k0 << 6;                  // tlo = 0
        #pragma unroll 4
        for (int u = 0; u <= slh; ++u) {
            int low = ((hi | (k2v - 2 * u)) ^ sw9) ^ (u << 1);
            float2 zz = Zc[cb + (u << 9) + low];
            float cou = ce * HR - se * HI;       // odd-sample window angle
            ae += zz.x * (1.f - ce);
            ao += zz.y * (1.f - cou);
            float nc = se; se = -ce; ce = nc;    // rotate -pi/2 (exact)
        }
        ae *= 0.015625f; ao *= 0.015625f;        // sqrt(1024)*0.5/512/2 folded
        int s = S0 + (pi << 1);
        int o = bc * LOUT + (s - 512);
        if (pi >= 384) {                         // sl in [768,1024): group-exclusive
            reinterpret_cast<float2*>(out)[o >> 1] = make_float2(ae, ao);
        } else if (s >= 512) {                   // head seam / head-trim boundary
            atomicAdd(&out[o],     ae);
            atomicAdd(&out[o + 1], ao);
        }
    }

    // r1 + r2 (shared setup)
    {
        const int pi = tid + 512;                // [512,1024)
        const int slh = pi >> 7;                 // 4..7
        const int tlo = slh - 3;                 // 1..4
        const int m0 = pi - (tlo << 7);          // in [384,512)
        const int k0 = m0 & 7;
        const int hi = ((m0 >> 3) & 7) << 3;
        const int k2v = m0 >> 6;
        const int sw9 = (9 * k0) & 63;
        float se0, ce0;
        __sincosf((float)m0 * A512, &se0, &ce0);
        const float ce = ce0, se = se0;
        const int cb = (tlo << 9) + (k0 << 6);

        // r1: always 4 taps, static sign permutations, no predicates
        {
            float ae = 0.f, ao = 0.f;
            #pragma unroll
            for (int u = 0; u < 4; ++u) {
                int low = ((hi | (k2v - 2 * u)) ^ sw9) ^ ((tlo + u) << 1);
                float2 zz = Zc[cb + (u << 9) + low];
                float cu = (u == 0) ? ce : (u == 1) ? se : (u == 2) ? -ce : -se;
                float su = (u == 0) ? se : (u == 1) ? -ce : (u == 2) ? -se : ce;
                float cou = cu * HR - su * HI;
                ae += zz.x * (1.f - cu);
                ao += zz.y * (1.f - cou);
            }
            ae *= 0.015625f; ao *= 0.015625f;
            int s = S0 + (pi << 1);
            reinterpret_cast<float2*>(out)[(bc * LOUT + (s - 512)) >> 1] = make_float2(ae, ao);
        }

        // r2: pi2 = pi + 512 in [1024,1408), frames tlo+4..7 (1-3 taps, wave-uniform)
        if (tid < 384) {
            const int ntap = 4 - tlo;            // 3,2,1
            float ce2 = ce, se2 = se;
            float ae = 0.f, ao = 0.f;
            const int cb2 = cb + (4 << 9);
            #pragma unroll 3
            for (int u = 0; u < ntap; ++u) {
                int low = ((hi | (k2v - 2 * u)) ^ sw9) ^ ((tlo + 4 + u) << 1);
                float2 zz = Zc[cb2 + (u << 9) + low];
                float cou = ce2 * HR - se2 * HI;
                ae += zz.x * (1.f - ce2);
                ao += zz.y * (1.f - cou);
                float nc = se2; se2 = -ce2; ce2 = nc;
            }
            ae *= 0.015625f; ao *= 0.015625f;
            int s = S0 + ((pi + 512) << 1);      // >= 2048, always >= 512
            int o = bc * LOUT + (s - 512);
            atomicAdd(&out[o],     ae);          // tail seam with next tile
            atomicAdd(&out[o + 1], ao);
        }
    }
}

extern "C" void kernel_launch(void* const* d_in, const int* in_sizes, int n_in,
                              void* d_out, int out_size, void* d_ws, size_t ws_size,
                              hipStream_t stream) {
    const float2* x = (const float2*)d_in[0];
    float* out = (float*)d_out;
    (void)in_sizes; (void)n_in; (void)d_ws; (void)ws_size;

    hipMemsetAsync(d_out, 0, (size_t)out_size * sizeof(float), stream);

    dim3 grid(TFRAMES / NT_TILE, 64);   // 128 tiles x 64 (B*C) rows
    dim3 block(512);
    istft_kernel<<<grid, block, 0, stream>>>(x, out);
}